// Round 11
// baseline (377.823 us; speedup 1.0000x reference)
//
#include <hip/hip_runtime.h>
#include <hip/hip_bf16.h>

#define N_STATE 1024
#define N_HEAD  16
#define D_HEAD  64
#define BATCH   8
#define SEQ     1500
#define ROWS    (BATCH*SEQ)   // 12000
#define SVP     1536          // padded seq stride for V^T
#define MTILES  94            // ceil(ROWS/128)

#define BM 128
#define BN 128
#define BK 32     // fallback kernels
#define BK2 64    // fast kernels

typedef __bf16 bf16x8 __attribute__((ext_vector_type(8)));
typedef __bf16 bf16x4 __attribute__((ext_vector_type(4)));
typedef float  f32x4  __attribute__((ext_vector_type(4)));

__device__ __forceinline__ f32x4 mfma16(bf16x8 a, bf16x8 b, f32x4 c) {
  return __builtin_amdgcn_mfma_f32_16x16x32_bf16(a, b, c, 0, 0, 0);
}

// Async global->LDS DMA, 16 B/lane; LDS dest wave-uniform, lane i -> +i*16.
__device__ __forceinline__ void gl_lds16(const void* g, void* l) {
  __builtin_amdgcn_global_load_lds(
      (const __attribute__((address_space(1))) unsigned int*)g,
      (__attribute__((address_space(3))) unsigned int*)l, 16, 0, 0);
}

// ---------------------------------------------------------------------------
// fp32 -> bf16 pre-convert: x -> xb, {Wq,Wk,Wv,Wo} -> wb[4]. Memory-bound.
// ---------------------------------------------------------------------------
__global__ __launch_bounds__(256)
void cvt_all(const float* __restrict__ x,  const float* __restrict__ wq,
             const float* __restrict__ wk, const float* __restrict__ wv,
             const float* __restrict__ wo,
             __bf16* __restrict__ xb, __bf16* __restrict__ wb)
{
  const int which = blockIdx.y;
  const float* src;
  __bf16* dst;
  size_t n;
  if (which == 0) { src = x; dst = xb; n = (size_t)ROWS * N_STATE; }
  else {
    src = (which == 1) ? wq : (which == 2) ? wk : (which == 3) ? wv : wo;
    dst = wb + (size_t)(which - 1) * N_STATE * N_STATE;
    n = (size_t)N_STATE * N_STATE;
  }
  const size_t stride = (size_t)gridDim.x * 256 * 4;
  for (size_t i = ((size_t)blockIdx.x * 256 + threadIdx.x) * 4; i < n; i += stride) {
    const f32x4 v = *(const f32x4*)(src + i);
    bf16x4 c; c[0]=(__bf16)v[0]; c[1]=(__bf16)v[1]; c[2]=(__bf16)v[2]; c[3]=(__bf16)v[3];
    *(bf16x4*)(dst + i) = c;
  }
}

// ---------------------------------------------------------------------------
// FAST QKV projection, BK2=64 (validated round 10): global_load_lds staging,
// mod-8 XOR swizzle, XCD-banded tile mapping.
// ---------------------------------------------------------------------------
__global__ __launch_bounds__(256)
void qkv_fast(const __bf16* __restrict__ xb, const __bf16* __restrict__ wb,
              const float* __restrict__ bq, const float* __restrict__ bv,
              __bf16* __restrict__ q_ws, __bf16* __restrict__ k_ws,
              __bf16* __restrict__ vt_ws)
{
  const int xcd = blockIdx.x & 7;
  const int jj  = blockIdx.x >> 3;
  const int nt  = jj & 7;
  const int mt  = (jj >> 3) * 8 + xcd;
  if (mt >= MTILES) return;

  __shared__ __bf16 lA[BM * BK2];
  __shared__ __bf16 lB[BN * BK2];
  const int which = blockIdx.z;
  const __bf16* W = wb + (size_t)which * N_STATE * N_STATE;

  const int tid = threadIdx.x;
  const int lane = tid & 63, wave = tid >> 6;
  const int l15 = lane & 15, quad = lane >> 4;
  const int wr = wave >> 1, wc = wave & 1;

  f32x4 acc[4][4] = {};

  for (int k0 = 0; k0 < N_STATE; k0 += BK2) {
#pragma unroll
    for (int t = 0; t < 4; ++t) {
      const int c = wave * 4 + t;
      const int s = c * 64 + lane;
      const int row = s >> 3;
      const int sw  = (lane & 7) ^ (row & 7);
      const int ga = min(mt * BM + row, ROWS - 1);
      gl_lds16(xb + (size_t)ga * N_STATE + k0 + sw * 8, (__bf16*)lA + c * 512);
      const int gb = nt * BN + row;
      gl_lds16(W + (size_t)gb * N_STATE + k0 + sw * 8, (__bf16*)lB + c * 512);
    }
    __syncthreads();
#pragma unroll
    for (int h = 0; h < 2; ++h) {
      bf16x8 af[4], bfr[4];
#pragma unroll
      for (int i = 0; i < 4; ++i) {
        const int ra = wr * 64 + i * 16 + l15;
        const int rb = wc * 64 + i * 16 + l15;
        af[i]  = *(const bf16x8*)&lA[ra * BK2 + (((h * 4 + quad) ^ (ra & 7)) * 8)];
        bfr[i] = *(const bf16x8*)&lB[rb * BK2 + (((h * 4 + quad) ^ (rb & 7)) * 8)];
      }
      if (which != 2) {
#pragma unroll
        for (int i = 0; i < 4; ++i)
#pragma unroll
          for (int j = 0; j < 4; ++j)
            acc[i][j] = mfma16(af[i], bfr[j], acc[i][j]);
      } else {
#pragma unroll
        for (int i = 0; i < 4; ++i)
#pragma unroll
          for (int j = 0; j < 4; ++j)
            acc[i][j] = mfma16(bfr[j], af[i], acc[i][j]);
      }
    }
    __syncthreads();
  }

  if (which != 2) {
#pragma unroll
    for (int i = 0; i < 4; ++i) {
      const int mrow = mt * BM + wr * 64 + i * 16 + quad * 4;
#pragma unroll
      for (int j = 0; j < 4; ++j) {
        const int col = nt * BN + wc * 64 + j * 16 + l15;
        const int h = col >> 6, d = col & 63;
        const float badd = (which == 0) ? bq[col] : 0.0f;
        __bf16* dst = (which == 0) ? q_ws : k_ws;
#pragma unroll
        for (int r = 0; r < 4; ++r) {
          const int row = mrow + r;
          if (row < ROWS) {
            const int b = row / SEQ, s = row % SEQ;
            dst[(((size_t)(b * N_HEAD + h)) * SEQ + s) * D_HEAD + d] =
                (__bf16)(acc[i][j][r] + badd);
          }
        }
      }
    }
  } else {
#pragma unroll
    for (int i = 0; i < 4; ++i) {
      const int sg = mt * BM + wr * 64 + i * 16 + l15;
      const bool valid = sg < ROWS;
      const int b = sg / SEQ, srow = sg % SEQ;
#pragma unroll
      for (int j = 0; j < 4; ++j) {
        const int dbase = nt * BN + wc * 64 + j * 16 + quad * 4;
#pragma unroll
        for (int r = 0; r < 4; ++r) {
          const int d = dbase + r;
          const int h = d >> 6, dd = d & 63;
          if (valid)
            vt_ws[(((size_t)(b * N_HEAD + h)) * D_HEAD + dd) * SVP + srow] =
                (__bf16)(acc[i][j][r] + bv[d]);
        }
      }
    }
  }
}

// ---------------------------------------------------------------------------
// FAST output projection, BK2=64 (validated round 10).
// ---------------------------------------------------------------------------
__global__ __launch_bounds__(256)
void out_fast(const __bf16* __restrict__ a_in, const __bf16* __restrict__ wob,
              const float* __restrict__ bo, float* __restrict__ out)
{
  const int xcd = blockIdx.x & 7;
  const int jj  = blockIdx.x >> 3;
  const int nt  = jj & 7;
  const int mt  = (jj >> 3) * 8 + xcd;
  if (mt >= MTILES) return;

  __shared__ __bf16 lA[BM * BK2];
  __shared__ __bf16 lB[BN * BK2];
  const int tid = threadIdx.x;
  const int lane = tid & 63, wave = tid >> 6;
  const int l15 = lane & 15, quad = lane >> 4;
  const int wr = wave >> 1, wc = wave & 1;

  f32x4 acc[4][4] = {};

  for (int k0 = 0; k0 < N_STATE; k0 += BK2) {
#pragma unroll
    for (int t = 0; t < 4; ++t) {
      const int c = wave * 4 + t;
      const int s = c * 64 + lane;
      const int row = s >> 3;
      const int sw  = (lane & 7) ^ (row & 7);
      const int ga = min(mt * BM + row, ROWS - 1);
      gl_lds16(a_in + (size_t)ga * N_STATE + k0 + sw * 8, (__bf16*)lA + c * 512);
      const int gb = nt * BN + row;
      gl_lds16(wob + (size_t)gb * N_STATE + k0 + sw * 8, (__bf16*)lB + c * 512);
    }
    __syncthreads();
#pragma unroll
    for (int h = 0; h < 2; ++h) {
      bf16x8 af[4], bfr[4];
#pragma unroll
      for (int i = 0; i < 4; ++i) {
        const int ra = wr * 64 + i * 16 + l15;
        const int rb = wc * 64 + i * 16 + l15;
        af[i]  = *(const bf16x8*)&lA[ra * BK2 + (((h * 4 + quad) ^ (ra & 7)) * 8)];
        bfr[i] = *(const bf16x8*)&lB[rb * BK2 + (((h * 4 + quad) ^ (rb & 7)) * 8)];
      }
#pragma unroll
      for (int i = 0; i < 4; ++i)
#pragma unroll
        for (int j = 0; j < 4; ++j)
          acc[i][j] = mfma16(af[i], bfr[j], acc[i][j]);
    }
    __syncthreads();
  }

#pragma unroll
  for (int i = 0; i < 4; ++i) {
    const int mrow = mt * BM + wr * 64 + i * 16 + quad * 4;
#pragma unroll
    for (int j = 0; j < 4; ++j) {
      const int col = nt * BN + wc * 64 + j * 16 + l15;
      const float badd = bo[col];
#pragma unroll
      for (int r = 0; r < 4; ++r) {
        const int row = mrow + r;
        if (row < ROWS)
          out[(size_t)row * N_STATE + col] = acc[i][j][r] + badd;
      }
    }
  }
}

// ---------------------------------------------------------------------------
// FALLBACK QKV projection (round-6 validated).
// ---------------------------------------------------------------------------
__global__ __launch_bounds__(256)
void qkv_gemm(const float* __restrict__ x,
              const float* __restrict__ Wq, const float* __restrict__ bq,
              const float* __restrict__ Wk,
              const float* __restrict__ Wv, const float* __restrict__ bv,
              __bf16* __restrict__ q_ws, __bf16* __restrict__ k_ws,
              __bf16* __restrict__ vt_ws)
{
  __shared__ __bf16 lA[BM * BK];
  __shared__ __bf16 lB[BN * BK];
  const int which = blockIdx.z;
  const float* W    = (which == 0) ? Wq : (which == 1) ? Wk : Wv;
  const float* bias = (which == 0) ? bq : (which == 2) ? bv : nullptr;

  const int mt = blockIdx.x, nt = blockIdx.y;
  const int tid = threadIdx.x;
  const int lane = tid & 63, wave = tid >> 6;
  const int l15 = lane & 15, quad = lane >> 4;
  const int wr = wave >> 1, wc = wave & 1;

  f32x4 acc[4][4] = {};

  for (int k0 = 0; k0 < N_STATE; k0 += BK) {
#pragma unroll
    for (int it = 0; it < 4; ++it) {
      const int s = tid + it * 256;
      const int row = s >> 3, seg = s & 7;
      const int ga = min(mt * BM + row, ROWS - 1);
      const f32x4 va = *(const f32x4*)(x + (size_t)ga * N_STATE + k0 + seg * 4);
      bf16x4 ca; ca[0]=(__bf16)va[0]; ca[1]=(__bf16)va[1];
                 ca[2]=(__bf16)va[2]; ca[3]=(__bf16)va[3];
      *(bf16x4*)&lA[row * BK + seg * 4] = ca;
      const int gb = nt * BM + row;
      const f32x4 vb = *(const f32x4*)(W + (size_t)gb * N_STATE + k0 + seg * 4);
      bf16x4 cb; cb[0]=(__bf16)vb[0]; cb[1]=(__bf16)vb[1];
                 cb[2]=(__bf16)vb[2]; cb[3]=(__bf16)vb[3];
      *(bf16x4*)&lB[row * BK + seg * 4] = cb;
    }
    __syncthreads();
    bf16x8 af[4], bfr[4];
#pragma unroll
    for (int i = 0; i < 4; ++i) {
      af[i]  = *(const bf16x8*)&lA[(wr * 64 + i * 16 + l15) * BK + quad * 8];
      bfr[i] = *(const bf16x8*)&lB[(wc * 64 + i * 16 + l15) * BK + quad * 8];
    }
    if (which != 2) {
#pragma unroll
      for (int i = 0; i < 4; ++i)
#pragma unroll
        for (int j = 0; j < 4; ++j)
          acc[i][j] = mfma16(af[i], bfr[j], acc[i][j]);
    } else {
#pragma unroll
      for (int i = 0; i < 4; ++i)
#pragma unroll
        for (int j = 0; j < 4; ++j)
          acc[i][j] = mfma16(bfr[j], af[i], acc[i][j]);
    }
    __syncthreads();
  }

  if (which != 2) {
#pragma unroll
    for (int i = 0; i < 4; ++i) {
      const int mrow = mt * BM + wr * 64 + i * 16 + quad * 4;
#pragma unroll
      for (int j = 0; j < 4; ++j) {
        const int col = nt * BN + wc * 64 + j * 16 + l15;
        const int h = col >> 6, d = col & 63;
        const float badd = bias ? bias[col] : 0.0f;
        __bf16* dst = (which == 0) ? q_ws : k_ws;
#pragma unroll
        for (int r = 0; r < 4; ++r) {
          const int row = mrow + r;
          if (row < ROWS) {
            const int b = row / SEQ, s = row % SEQ;
            dst[(((size_t)(b * N_HEAD + h)) * SEQ + s) * D_HEAD + d] =
                (__bf16)(acc[i][j][r] + badd);
          }
        }
      }
    }
  } else {
#pragma unroll
    for (int i = 0; i < 4; ++i) {
      const int sg = mt * BM + wr * 64 + i * 16 + l15;
      const bool valid = sg < ROWS;
      const int b = sg / SEQ, srow = sg % SEQ;
#pragma unroll
      for (int j = 0; j < 4; ++j) {
        const int dbase = nt * BN + wc * 64 + j * 16 + quad * 4;
#pragma unroll
        for (int r = 0; r < 4; ++r) {
          const int d = dbase + r;
          const int h = d >> 6, dd = d & 63;
          if (valid)
            vt_ws[(((size_t)(b * N_HEAD + h)) * D_HEAD + dd) * SVP + srow] =
                (__bf16)(acc[i][j][r] + bias[d]);
        }
      }
    }
  }
}

// ---------------------------------------------------------------------------
// Flash attention v4, causal: 128 queries per block (two 64-query sub-tiles
// per wave over the SAME staged K/V tile) — halves staging bytes and barrier
// count per query vs v3. Per sub-tile the math is byte-identical to the
// validated v3: S^T = K*Q^T (query=l15), in-lane softmax + 2 shfls,
// O^T += V^T * P^T. lPw reused sequentially (same-wave LDS ordering).
// ---------------------------------------------------------------------------
__global__ __launch_bounds__(256)
void flash_attn(const __bf16* __restrict__ q_ws, const __bf16* __restrict__ k_ws,
                const __bf16* __restrict__ vt_ws, __bf16* __restrict__ attn)
{
  __shared__ __align__(16) __bf16 lK[8 * 512];
  __shared__ __align__(16) __bf16 lV[8 * 512];
  __shared__ __align__(16) __bf16 lP[4 * 16 * 72];
  const int bh = blockIdx.x;
  const int qt = gridDim.y - 1 - blockIdx.y;   // heavy tiles first
  const int tid = threadIdx.x, lane = tid & 63, wave = tid >> 6;
  const int l15 = lane & 15, quad = lane >> 4;
  const __bf16* Q  = q_ws  + (size_t)bh * SEQ * D_HEAD;
  const __bf16* K  = k_ws  + (size_t)bh * SEQ * D_HEAD;
  const __bf16* Vt = vt_ws + (size_t)bh * D_HEAD * SVP;
  __bf16* lPw = lP + wave * 16 * 72;

  const int q0 = qt * 128;
  const float NEG = -1.0e30f;
  const float scale = 0.125f;

  int wq0[2], query[2];
  bf16x8 qa[2][2];
  f32x4 o[2][4] = {};
  float m_i[2], l_i[2];
#pragma unroll
  for (int s = 0; s < 2; ++s) {
    wq0[s] = q0 + s * 64 + wave * 16;
    query[s] = wq0[s] + l15;
    const int qload = min(query[s], SEQ - 1);
    qa[s][0] = *(const bf16x8*)(Q + (size_t)qload * D_HEAD + quad * 8);
    qa[s][1] = *(const bf16x8*)(Q + (size_t)qload * D_HEAD + 32 + quad * 8);
    m_i[s] = NEG; l_i[s] = 0.0f;
  }

  const int kmax = min(q0 + 127, SEQ - 1);

  for (int kt = 0; kt <= kmax; kt += 64) {
    // ---- DMA staging (identical to v3) ----
#pragma unroll
    for (int t = 0; t < 2; ++t) {
      const int c = wave * 2 + t;
      const int gk = min(kt + lane, SEQ - 1);
      gl_lds16(K + (size_t)gk * D_HEAD + c * 8, (__bf16*)lK + c * 512);
      gl_lds16(Vt + (size_t)lane * SVP + kt + c * 8, (__bf16*)lV + c * 512);
    }
    __syncthreads();

#pragma unroll
    for (int s = 0; s < 2; ++s) {
      if (kt <= wq0[s] + 15) {          // wave-uniform causal skip
        f32x4 sg[4] = {};
#pragma unroll
        for (int g = 0; g < 4; ++g) {
          const bf16x8 k0 = *(const bf16x8*)&lK[quad * 512 + (g * 16 + l15) * 8];
          const bf16x8 k1 = *(const bf16x8*)&lK[(4 + quad) * 512 + (g * 16 + l15) * 8];
          sg[g] = mfma16(k0, qa[s][0], sg[g]);
          sg[g] = mfma16(k1, qa[s][1], sg[g]);
        }
        const bool fullvis = (kt + 63 <= wq0[s]) && (kt + 63 < SEQ);
        float tmax = NEG;
#pragma unroll
        for (int g = 0; g < 4; ++g)
#pragma unroll
          for (int r = 0; r < 4; ++r) {
            float v = sg[g][r] * scale;
            if (!fullvis) {
              const int key = kt + g * 16 + quad * 4 + r;
              v = (key <= query[s] && key < SEQ) ? v : NEG;
            }
            sg[g][r] = v;
            tmax = fmaxf(tmax, v);
          }
        tmax = fmaxf(tmax, __shfl_xor(tmax, 16));
        tmax = fmaxf(tmax, __shfl_xor(tmax, 32));
        const float mnew = fmaxf(m_i[s], tmax);
        const float alpha = __expf(m_i[s] - mnew);
        float rsum = 0.0f;
#pragma unroll
        for (int g = 0; g < 4; ++g) {
          bf16x4 pk;
#pragma unroll
          for (int r = 0; r < 4; ++r) {
            const float e = __expf(sg[g][r] - mnew);
            rsum += e;
            pk[r] = (__bf16)e;
          }
          *(bf16x4*)&lPw[l15 * 72 + g * 16 + quad * 4] = pk;
        }
        rsum += __shfl_xor(rsum, 16);
        rsum += __shfl_xor(rsum, 32);
        l_i[s] = l_i[s] * alpha + rsum;
        m_i[s] = mnew;
#pragma unroll
        for (int nn = 0; nn < 4; ++nn)
#pragma unroll
          for (int r = 0; r < 4; ++r) o[s][nn][r] *= alpha;

#pragma unroll
        for (int h = 0; h < 2; ++h) {
          const bf16x8 pb = *(const bf16x8*)&lPw[l15 * 72 + h * 32 + quad * 8];
#pragma unroll
          for (int nn = 0; nn < 4; ++nn) {
            const bf16x8 va =
                *(const bf16x8*)&lV[(h * 4 + quad) * 512 + (nn * 16 + l15) * 8];
            o[s][nn] = mfma16(va, pb, o[s][nn]);
          }
        }
      }
    }
    __syncthreads();
  }

  const int b = bh >> 4, hh = bh & 15;
#pragma unroll
  for (int s = 0; s < 2; ++s) {
    if (query[s] < SEQ) {
      const float inv = 1.0f / l_i[s];
#pragma unroll
      for (int nn = 0; nn < 4; ++nn) {
        bf16x4 ov;
#pragma unroll
        for (int r = 0; r < 4; ++r) ov[r] = (__bf16)(o[s][nn][r] * inv);
        *(bf16x4*)&attn[(((size_t)(b * SEQ + query[s])) * N_HEAD + hh) * D_HEAD +
                        nn * 16 + quad * 4] = ov;
      }
    }
  }
}

// ---------------------------------------------------------------------------
// FALLBACK output projection (round-6 validated).
// ---------------------------------------------------------------------------
__global__ __launch_bounds__(256)
void out_gemm(const __bf16* __restrict__ a_in, const float* __restrict__ Wo,
              const float* __restrict__ bo, float* __restrict__ out)
{
  __shared__ __bf16 lA[BM * BK];
  __shared__ __bf16 lB[BN * BK];
  const int mt = blockIdx.x, nt = blockIdx.y;
  const int tid = threadIdx.x;
  const int lane = tid & 63, wave = tid >> 6;
  const int l15 = lane & 15, quad = lane >> 4;
  const int wr = wave >> 1, wc = wave & 1;

  f32x4 acc[4][4] = {};

  for (int k0 = 0; k0 < N_STATE; k0 += BK) {
#pragma unroll
    for (int it = 0; it < 2; ++it) {
      const int s = tid + it * 256;
      const int row = s >> 2, seg = s & 3;
      const int ga = min(mt * BM + row, ROWS - 1);
      *(bf16x8*)&lA[row * BK + seg * 8] =
          *(const bf16x8*)(a_in + (size_t)ga * N_STATE + k0 + seg * 8);
    }
#pragma unroll
    for (int it = 0; it < 4; ++it) {
      const int s = tid + it * 256;
      const int row = s >> 3, seg = s & 7;
      const int gb = nt * BM + row;
      const f32x4 vb = *(const f32x4*)(Wo + (size_t)gb * N_STATE + k0 + seg * 4);
      bf16x4 cb; cb[0]=(__bf16)vb[0]; cb[1]=(__bf16)vb[1];
                 cb[2]=(__bf16)vb[2]; cb[3]=(__bf16)vb[3];
      *(bf16x4*)&lB[row * BK + seg * 4] = cb;
    }
    __syncthreads();
    bf16x8 af[4], bfr[4];
#pragma unroll
    for (int i = 0; i < 4; ++i) {
      af[i]  = *(const bf16x8*)&lA[(wr * 64 + i * 16 + l15) * BK + quad * 8];
      bfr[i] = *(const bf16x8*)&lB[(wc * 64 + i * 16 + l15) * BK + quad * 8];
    }
#pragma unroll
    for (int i = 0; i < 4; ++i)
#pragma unroll
      for (int j = 0; j < 4; ++j)
        acc[i][j] = mfma16(af[i], bfr[j], acc[i][j]);
    __syncthreads();
  }

#pragma unroll
  for (int i = 0; i < 4; ++i) {
    const int mrow = mt * BM + wr * 64 + i * 16 + quad * 4;
#pragma unroll
    for (int j = 0; j < 4; ++j) {
      const int col = nt * BN + wc * 64 + j * 16 + l15;
      const float badd = bo[col];
#pragma unroll
      for (int r = 0; r < 4; ++r) {
        const int row = mrow + r;
        if (row < ROWS)
          out[(size_t)row * N_STATE + col] = acc[i][j][r] + badd;
      }
    }
  }
}

// ---------------------------------------------------------------------------
extern "C" void kernel_launch(void* const* d_in, const int* in_sizes, int n_in,
                              void* d_out, int out_size, void* d_ws, size_t ws_size,
                              hipStream_t stream) {
  const float* x  = (const float*)d_in[0];
  // d_in[1] = mask: causal, implemented analytically — not read.
  const float* Wq = (const float*)d_in[2];
  const float* bq = (const float*)d_in[3];
  const float* Wk = (const float*)d_in[4];
  const float* Wv = (const float*)d_in[5];
  const float* bv = (const float*)d_in[6];
  const float* Wo = (const float*)d_in[7];
  const float* bo = (const float*)d_in[8];
  float* out = (float*)d_out;

  // ws: [q][k][vt][attn|xb][wb]  (xb shares the attn region: qkv finishes
  // reading xb before flash writes attn — stream-ordered).
  const size_t chunk  = (size_t)ROWS * N_STATE;                  // 12.288M
  const size_t vchunk = (size_t)BATCH * N_HEAD * D_HEAD * SVP;   // 12.583M
  const size_t wchunk = (size_t)4 * N_STATE * N_STATE;           //  4.194M
  __bf16* q_ws  = (__bf16*)d_ws;
  __bf16* k_ws  = q_ws + chunk;
  __bf16* vt_ws = k_ws + chunk;
  __bf16* attn  = vt_ws + vchunk;
  __bf16* xb    = attn;                 // overlap
  __bf16* wb    = attn + chunk;
  const size_t need = (3 * chunk + vchunk + wchunk) * sizeof(__bf16);  // 107.3 MB

  const int MT = (ROWS + BM - 1) / BM;   // 94
  if (ws_size >= need) {
    cvt_all<<<dim3(1024, 5), 256, 0, stream>>>(x, Wq, Wk, Wv, Wo, xb, wb);
    qkv_fast<<<dim3(768, 1, 3), 256, 0, stream>>>(
        xb, wb, bq, bv, q_ws, k_ws, vt_ws);
    flash_attn<<<dim3(BATCH * N_HEAD, (SEQ + 127) / 128), 256, 0, stream>>>(
        q_ws, k_ws, vt_ws, attn);
    out_fast<<<dim3(768, 1, 1), 256, 0, stream>>>(
        attn, wb + (size_t)3 * N_STATE * N_STATE, bo, out);
  } else {
    qkv_gemm<<<dim3(MT, N_STATE / BN, 3), 256, 0, stream>>>(
        x, Wq, bq, Wk, Wv, bv, q_ws, k_ws, vt_ws);
    flash_attn<<<dim3(BATCH * N_HEAD, (SEQ + 127) / 128), 256, 0, stream>>>(
        q_ws, k_ws, vt_ws, attn);
    out_gemm<<<dim3(MT, N_STATE / BN), 256, 0, stream>>>(attn, Wo, bo, out);
  }
}